// Round 10
// baseline (351.232 us; speedup 1.0000x reference)
//
#include <hip/hip_runtime.h>
#include <hip/hip_fp16.h>

#define N 1024
#define D 128

// ---------------- proj v1 (round-5 proven): Qh,Kh,Ah,Bh (f16) = z@{Wq,Wk,W1a,W1b} ----------------
// + zeroes the 32 per-band ticket counters for the fused kernel (stream order = visibility).
__global__ __launch_bounds__(256) void proj_kernel(
    const float* __restrict__ z,
    const float* __restrict__ Wq, const float* __restrict__ bq,
    const float* __restrict__ Wk, const float* __restrict__ bk,
    const float* __restrict__ W1, const float* __restrict__ b1,
    __half* __restrict__ Qh, __half* __restrict__ Kh,
    __half* __restrict__ Ah, __half* __restrict__ Bh,
    unsigned* __restrict__ cnt)
{
    if (blockIdx.x == 0 && threadIdx.x < 32) cnt[threadIdx.x] = 0;

    const int d  = threadIdx.x & (D - 1);
    const int h  = threadIdx.x >> 7;              // wave-uniform: 0 -> Q/K, 1 -> A/B
    const int r0 = blockIdx.x * 4;
    const float* __restrict__ Wa = h ? W1           : Wq;
    const float* __restrict__ Wb = h ? (W1 + D * D) : Wk;

    float acc0[4] = {0,0,0,0};
    float acc1[4] = {0,0,0,0};

    for (int c = 0; c < D / 4; ++c) {
        float4 zr[4];
#pragma unroll
        for (int r = 0; r < 4; ++r)
            zr[r] = *(const float4*)&z[(r0 + r) * D + c * 4];
#pragma unroll
        for (int q = 0; q < 4; ++q) {
            const int k = c * 4 + q;
            const float wa = Wa[k * D + d];
            const float wb = Wb[k * D + d];
#pragma unroll
            for (int r = 0; r < 4; ++r) {
                const float zv = (q == 0) ? zr[r].x : (q == 1) ? zr[r].y : (q == 2) ? zr[r].z : zr[r].w;
                acc0[r] = fmaf(zv, wa, acc0[r]);
                acc1[r] = fmaf(zv, wb, acc1[r]);
            }
        }
    }
    if (h == 0) {
        const float c0 = bq[d], c1 = bk[d];
        const float scale = 0.08838834764831845f;   // 1/sqrt(128), folded into Qh
#pragma unroll
        for (int r = 0; r < 4; ++r) {
            Qh[(r0 + r) * D + d] = __float2half((acc0[r] + c0) * scale);
            Kh[(r0 + r) * D + d] = __float2half(acc1[r] + c1);
        }
    } else {
        const float c0 = b1[d];
#pragma unroll
        for (int r = 0; r < 4; ++r) {
            Ah[(r0 + r) * D + d] = __float2half(acc0[r] + c0);   // b1 folded
            Bh[(r0 + r) * D + d] = __float2half(acc1[r]);
        }
    }
}

union H2x4 { uint4 u; __half2 h[4]; };

__device__ __forceinline__ float fdot2_acc(__half2 a, __half2 b, float c) {
#if __has_builtin(__builtin_amdgcn_fdot2)
    typedef _Float16 v2h __attribute__((ext_vector_type(2)));
    union { __half2 h; v2h v; } ua, ub;
    ua.h = a; ub.h = b;
    return __builtin_amdgcn_fdot2(ua.v, ub.v, c, false);
#else
    return fmaf(__low2float(a), __low2float(b),
           fmaf(__high2float(a), __high2float(b), c));
#endif
}

#define HP 136   // halves pitch: 272 B rows (16B-aligned); 2-way bank alias only (free)

// ---------------- fused: score tiles (y<32) + ticket topk | pair tiles (y>=32) ----------------
// One dispatch replaces score+topk+pair (launch overhead ~22us/dispatch, solved from R5/R6).
// Score band completion tracked by per-band device atomics; the 32nd finisher re-reads its
// 32-row band and runs the proven per-row topk (4 waves x 8 rows; hidden under pair).
// XCD-coherence: writers do {stores, __threadfence, atomicAdd}; the winner does
// {read ticket, __threadfence (acquire: invalidates this XCD's stale L1/L2 lines), re-read}.
__global__ __launch_bounds__(256) void fused_kernel(
    const __half* __restrict__ Qh, const __half* __restrict__ Kh,
    const float* __restrict__ dist,
    const __half* __restrict__ Ah, const __half* __restrict__ Bh,
    const float* __restrict__ W2, const float* __restrict__ b2,
    unsigned* __restrict__ cnt, float* __restrict__ out)
{
    __shared__ __align__(16) unsigned char lds[18496];   // union arena: score 17408B | pair 17952B
    __shared__ unsigned s_old;
    const int tid = threadIdx.x;
    const int tx = tid & 15, ty = tid >> 4;

    if (blockIdx.y < 32) {
        // ================= score tile (proven round 5) =================
        __half* Qs = (__half*)lds;
        __half* Ks = (__half*)(lds + 8704);
        const int bi = blockIdx.y * 32, bj = blockIdx.x * 32;

#pragma unroll
        for (int t = 0; t < 2; ++t) {
            const int e = t * 256 + tid;
            const int row = e >> 4, c = e & 15;
            *(uint4*)&Qs[row * HP + c * 8] = *(const uint4*)&Qh[(size_t)(bi + row) * D + c * 8];
            *(uint4*)&Ks[row * HP + c * 8] = *(const uint4*)&Kh[(size_t)(bj + row) * D + c * 8];
        }
        __syncthreads();

        float a00 = 0.f, a01 = 0.f, a10 = 0.f, a11 = 0.f;
#pragma unroll 4
        for (int c = 0; c < 16; ++c) {
            H2x4 q0, q1, k0, k1;
            q0.u = *(const uint4*)&Qs[ty * HP + c * 8];
            q1.u = *(const uint4*)&Qs[(ty + 16) * HP + c * 8];
            k0.u = *(const uint4*)&Ks[tx * HP + c * 8];
            k1.u = *(const uint4*)&Ks[(tx + 16) * HP + c * 8];
#pragma unroll
            for (int dp = 0; dp < 4; ++dp) {
                a00 = fdot2_acc(q0.h[dp], k0.h[dp], a00);
                a01 = fdot2_acc(q0.h[dp], k1.h[dp], a01);
                a10 = fdot2_acc(q1.h[dp], k0.h[dp], a10);
                a11 = fdot2_acc(q1.h[dp], k1.h[dp], a11);
            }
        }
        const int i0 = bi + ty, i1 = bi + ty + 16;
        const int j0 = bj + tx, j1 = bj + tx + 16;
        out[(size_t)i0 * N + j0] = a00 * __expf(-dist[(size_t)i0 * N + j0]);
        out[(size_t)i0 * N + j1] = a01 * __expf(-dist[(size_t)i0 * N + j1]);
        out[(size_t)i1 * N + j0] = a10 * __expf(-dist[(size_t)i1 * N + j0]);
        out[(size_t)i1 * N + j1] = a11 * __expf(-dist[(size_t)i1 * N + j1]);

        // ---- ticket: last finisher of this 32-row band runs topk ----
        __threadfence();                 // release: this block's S stores -> device visible
        __syncthreads();                 // all threads fenced before the atomic
        if (tid == 0) s_old = atomicAdd(&cnt[blockIdx.y], 1u);
        __syncthreads();
        if (s_old == 31u) {
            __threadfence();             // acquire: invalidate stale lines before re-read
            const int wv = tid >> 6, lane = tid & 63;
            for (int r8 = 0; r8 < 8; ++r8) {
                const int row = bi + wv * 8 + r8;
                float* sr = out + (size_t)row * N;

                float v[16];
#pragma unroll
                for (int c = 0; c < 4; ++c) {
                    const float4 f = *(const float4*)&sr[(c * 64 + lane) * 4];
                    v[c * 4 + 0] = f.x; v[c * 4 + 1] = f.y; v[c * 4 + 2] = f.z; v[c * 4 + 3] = f.w;
                }
                float m = v[0];
#pragma unroll
                for (int e = 1; e < 16; ++e) m = fmaxf(m, v[e]);
#pragma unroll
                for (int off = 1; off < 64; off <<= 1) m = fmaxf(m, __shfl_xor(m, off));
                float sum = 0.f;
#pragma unroll
                for (int e = 0; e < 16; ++e) sum += __expf(v[e] - m);
#pragma unroll
                for (int off = 1; off < 64; off <<= 1) sum += __shfl_xor(sum, off);
                const float inv = 1.0f / sum;

                unsigned key[16];
#pragma unroll
                for (int e = 0; e < 16; ++e) {
                    const int j = (((e >> 2) * 64 + lane) * 4) + (e & 3);
                    unsigned u = __float_as_uint(v[e]);
                    u = (u & 0x80000000u) ? ~u : (u | 0x80000000u);
                    key[e] = (u & 0xFFFFFC00u) | (unsigned)(N - 1 - j);
                }
                unsigned flags = 0;
                for (int it = 0; it < 32; ++it) {
                    unsigned best = key[0];
#pragma unroll
                    for (int e = 1; e < 16; ++e) best = (key[e] > best) ? key[e] : best;
#pragma unroll
                    for (int off = 1; off < 64; off <<= 1) {
                        const unsigned o = __shfl_xor(best, off);
                        if (o > best) best = o;
                    }
#pragma unroll
                    for (int e = 0; e < 16; ++e)
                        if (key[e] == best) { flags |= 1u << e; key[e] = 0u; }
                }
#pragma unroll
                for (int c = 0; c < 4; ++c) {
                    float4 o;
                    o.x = (flags & (1u << (c * 4 + 0))) ? __expf(v[c * 4 + 0] - m) * inv : 0.f;
                    o.y = (flags & (1u << (c * 4 + 1))) ? __expf(v[c * 4 + 1] - m) * inv : 0.f;
                    o.z = (flags & (1u << (c * 4 + 2))) ? __expf(v[c * 4 + 2] - m) * inv : 0.f;
                    o.w = (flags & (1u << (c * 4 + 3))) ? __expf(v[c * 4 + 3] - m) * inv : 0.f;
                    *(float4*)&sr[(c * 64 + lane) * 4] = o;
                }
            }
        }
    } else {
        // ================= pair tile (proven round 5) =================
        __half*  AsH = (__half*)lds;
        __half*  BsH = (__half*)(lds + 8704);
        __half2* Wh0 = (__half2*)(lds + 17408);   // 68 half2
        __half2* Wh1 = Wh0 + 68;
        const int bi = (blockIdx.y - 32) * 32, bj = blockIdx.x * 32;
        float* pout = out + (size_t)N * N;

#pragma unroll
        for (int t = 0; t < 2; ++t) {
            const int e = t * 256 + tid;
            const int row = e >> 4, c = e & 15;
            *(uint4*)&AsH[row * HP + c * 8] = *(const uint4*)&Ah[(size_t)(bi + row) * D + c * 8];
            *(uint4*)&BsH[row * HP + c * 8] = *(const uint4*)&Bh[(size_t)(bj + row) * D + c * 8];
        }
        // Wh[cls][dp] = {W2[2dp][cls]-W2[2dp][2], W2[2dp+1][cls]-W2[2dp+1][2]}  (no 0.5!)
        if (tid < 128) {
            const int cls = tid >> 6, dp = tid & 63;
            __half2* Wh = cls ? Wh1 : Wh0;
            Wh[dp] = __floats2half2_rn(W2[6 * dp + cls]     - W2[6 * dp + 2],
                                       W2[6 * dp + 3 + cls] - W2[6 * dp + 5]);
        }
        const float bb0 = b2[0] - b2[2], bb1 = b2[1] - b2[2];
        __syncthreads();

        float acc[4][2];
#pragma unroll
        for (int p = 0; p < 4; ++p) { acc[p][0] = bb0; acc[p][1] = bb1; }

        const __half2 C3  = __float2half2_rn(-0.1029434f);
        const __half2 C1  = __float2half2_rn(-2.3022082f);
        const __half2 ONE = __float2half2_rn(1.0f);

#pragma unroll 4
        for (int c = 0; c < 16; ++c) {
            H2x4 a0, a1, b0, b1, w0, w1;
            a0.u = *(const uint4*)&AsH[ty * HP + c * 8];
            a1.u = *(const uint4*)&AsH[(ty + 16) * HP + c * 8];
            b0.u = *(const uint4*)&BsH[tx * HP + c * 8];
            b1.u = *(const uint4*)&BsH[(tx + 16) * HP + c * 8];
            w0.u = *(const uint4*)&Wh0[c * 4];    // wave-uniform -> LDS broadcast
            w1.u = *(const uint4*)&Wh1[c * 4];
#pragma unroll
            for (int dp = 0; dp < 4; ++dp) {
                const __half2 aa[2] = { a0.h[dp], a1.h[dp] };
                const __half2 bb[2] = { b0.h[dp], b1.h[dp] };
                const __half2 wc0 = w0.h[dp], wc1 = w1.h[dp];
#pragma unroll
                for (int ii = 0; ii < 2; ++ii)
#pragma unroll
                    for (int jj = 0; jj < 2; ++jj) {
                        const __half2 x = __hadd2(aa[ii], bb[jj]);
                        const __half2 u = __hmul2(x, x);
                        const __half2 p = __hfma2(C3, u, C1);
                        const __half2 t = __hmul2(x, p);
                        const __half2 e = h2exp2(t);          // 2^t
                        const __half2 dn = __hadd2(e, ONE);
                        const __half2 r = h2rcp(dn);          // rcp(inf)=0 -> g=0 (correct)
                        const __half2 g = __hmul2(x, r);      // g = gelu(x)
                        float* l = acc[ii * 2 + jj];
                        l[0] = fdot2_acc(g, wc0, l[0]);
                        l[1] = fdot2_acc(g, wc1, l[1]);
                    }
            }
        }

#pragma unroll
        for (int ii = 0; ii < 2; ++ii)
#pragma unroll
            for (int jj = 0; jj < 2; ++jj) {
                const int i = bi + ty + 16 * ii;
                const int j = bj + tx + 16 * jj;
                const float* l = acc[ii * 2 + jj];
                const float l0 = l[0], l1 = l[1];                // l2 == 0
                const float mm = fmaxf(fmaxf(l0, l1), 0.f);
                const float e0 = __expf(l0 - mm), e1 = __expf(l1 - mm), e2 = __expf(-mm);
                const float inv2 = 1.0f / (e0 + e1 + e2);
                float* o = pout + ((size_t)i * N + j) * 3;
                o[0] = e0 * inv2; o[1] = e1 * inv2; o[2] = e2 * inv2;
            }
    }
}

extern "C" void kernel_launch(void* const* d_in, const int* in_sizes, int n_in,
                              void* d_out, int out_size, void* d_ws, size_t ws_size,
                              hipStream_t stream)
{
    const float* z    = (const float*)d_in[0];
    const float* dist = (const float*)d_in[1];
    const float* Wq   = (const float*)d_in[2];
    const float* bq   = (const float*)d_in[3];
    const float* Wk   = (const float*)d_in[4];
    const float* bk   = (const float*)d_in[5];
    const float* W1   = (const float*)d_in[6];
    const float* b1   = (const float*)d_in[7];
    const float* W2   = (const float*)d_in[8];
    const float* b2   = (const float*)d_in[9];

    float* out = (float*)d_out;
    __half* Qh = (__half*)d_ws;
    __half* Kh = Qh + (size_t)N * D;
    __half* Ah = Kh + (size_t)N * D;
    __half* Bh = Ah + (size_t)N * D;
    unsigned* cnt = (unsigned*)(Bh + (size_t)N * D);   // ws + 1MB, 32 words

    proj_kernel<<<N / 4, 256, 0, stream>>>(z, Wq, bq, Wk, bk, W1, b1, Qh, Kh, Ah, Bh, cnt);
    fused_kernel<<<dim3(32, 64), 256, 0, stream>>>(Qh, Kh, dist, Ah, Bh, W2, b2, cnt, out);
}

// Round 11
// 138.784 us; speedup vs baseline: 2.5308x; 2.5308x over previous
//
#include <hip/hip_runtime.h>
#include <hip/hip_fp16.h>

#define N 1024
#define D 128

// ---------------- proj v1 (round-5 proven): Qh,Kh,Ah,Bh (f16) = z@{Wq,Wk,W1a,W1b} ----------------
__global__ __launch_bounds__(256) void proj_kernel(
    const float* __restrict__ z,
    const float* __restrict__ Wq, const float* __restrict__ bq,
    const float* __restrict__ Wk, const float* __restrict__ bk,
    const float* __restrict__ W1, const float* __restrict__ b1,
    __half* __restrict__ Qh, __half* __restrict__ Kh,
    __half* __restrict__ Ah, __half* __restrict__ Bh)
{
    const int d  = threadIdx.x & (D - 1);
    const int h  = threadIdx.x >> 7;              // wave-uniform: 0 -> Q/K, 1 -> A/B
    const int r0 = blockIdx.x * 4;
    const float* __restrict__ Wa = h ? W1           : Wq;
    const float* __restrict__ Wb = h ? (W1 + D * D) : Wk;

    float acc0[4] = {0,0,0,0};
    float acc1[4] = {0,0,0,0};

    for (int c = 0; c < D / 4; ++c) {
        float4 zr[4];
#pragma unroll
        for (int r = 0; r < 4; ++r)
            zr[r] = *(const float4*)&z[(r0 + r) * D + c * 4];
#pragma unroll
        for (int q = 0; q < 4; ++q) {
            const int k = c * 4 + q;
            const float wa = Wa[k * D + d];
            const float wb = Wb[k * D + d];
#pragma unroll
            for (int r = 0; r < 4; ++r) {
                const float zv = (q == 0) ? zr[r].x : (q == 1) ? zr[r].y : (q == 2) ? zr[r].z : zr[r].w;
                acc0[r] = fmaf(zv, wa, acc0[r]);
                acc1[r] = fmaf(zv, wb, acc1[r]);
            }
        }
    }
    if (h == 0) {
        const float c0 = bq[d], c1 = bk[d];
        const float scale = 0.08838834764831845f;   // 1/sqrt(128), folded into Qh
#pragma unroll
        for (int r = 0; r < 4; ++r) {
            Qh[(r0 + r) * D + d] = __float2half((acc0[r] + c0) * scale);
            Kh[(r0 + r) * D + d] = __float2half(acc1[r] + c1);
        }
    } else {
        const float c0 = b1[d];
#pragma unroll
        for (int r = 0; r < 4; ++r) {
            Ah[(r0 + r) * D + d] = __float2half(acc0[r] + c0);   // b1 folded
            Bh[(r0 + r) * D + d] = __float2half(acc1[r]);
        }
    }
}

union H2x4 { uint4 u; __half2 h[4]; };

__device__ __forceinline__ float fdot2_acc(__half2 a, __half2 b, float c) {
#if __has_builtin(__builtin_amdgcn_fdot2)
    typedef _Float16 v2h __attribute__((ext_vector_type(2)));
    union { __half2 h; v2h v; } ua, ub;
    ua.h = a; ub.h = b;
    return __builtin_amdgcn_fdot2(ua.v, ub.v, c, false);
#else
    return fmaf(__low2float(a), __low2float(b),
           fmaf(__high2float(a), __high2float(b), c));
#endif
}

#define HP 136   // halves pitch: 272 B rows (16B-aligned); 2-way bank alias only (free)

// ---------------- scores: S = (Qh Kh^T) * exp(-dist), f16 fdot2 (proven round 5) ----------------
__global__ __launch_bounds__(256) void score_kernel(
    const __half* __restrict__ Qh, const __half* __restrict__ Kh,
    const float* __restrict__ dist, float* __restrict__ S)
{
    __shared__ __align__(16) __half Qs[32 * HP];
    __shared__ __align__(16) __half Ks[32 * HP];
    const int tid = threadIdx.x;
    const int bi = blockIdx.y * 32, bj = blockIdx.x * 32;
    const int tx = tid & 15, ty = tid >> 4;

#pragma unroll
    for (int t = 0; t < 2; ++t) {
        const int e = t * 256 + tid;
        const int row = e >> 4, c = e & 15;
        *(uint4*)&Qs[row * HP + c * 8] = *(const uint4*)&Qh[(size_t)(bi + row) * D + c * 8];
        *(uint4*)&Ks[row * HP + c * 8] = *(const uint4*)&Kh[(size_t)(bj + row) * D + c * 8];
    }
    __syncthreads();

    float a00 = 0.f, a01 = 0.f, a10 = 0.f, a11 = 0.f;

#pragma unroll 4
    for (int c = 0; c < 16; ++c) {      // 16 chunks x 8 dims
        H2x4 q0, q1, k0, k1;
        q0.u = *(const uint4*)&Qs[ty * HP + c * 8];
        q1.u = *(const uint4*)&Qs[(ty + 16) * HP + c * 8];
        k0.u = *(const uint4*)&Ks[tx * HP + c * 8];
        k1.u = *(const uint4*)&Ks[(tx + 16) * HP + c * 8];
#pragma unroll
        for (int dp = 0; dp < 4; ++dp) {
            a00 = fdot2_acc(q0.h[dp], k0.h[dp], a00);
            a01 = fdot2_acc(q0.h[dp], k1.h[dp], a01);
            a10 = fdot2_acc(q1.h[dp], k0.h[dp], a10);
            a11 = fdot2_acc(q1.h[dp], k1.h[dp], a11);
        }
    }

    const int i0 = bi + ty, i1 = bi + ty + 16;
    const int j0 = bj + tx, j1 = bj + tx + 16;
    S[(size_t)i0 * N + j0] = a00 * __expf(-dist[(size_t)i0 * N + j0]);
    S[(size_t)i0 * N + j1] = a01 * __expf(-dist[(size_t)i0 * N + j1]);
    S[(size_t)i1 * N + j0] = a10 * __expf(-dist[(size_t)i1 * N + j0]);
    S[(size_t)i1 * N + j1] = a11 * __expf(-dist[(size_t)i1 * N + j1]);
}

// ---------------- fused topk | pair: one dispatch, NO fences ----------------
// Both depend only on PREVIOUS dispatches (topk<-score, pair<-proj): kernel boundary
// provides all visibility. bid<1024: proven pair tile; bid>=1024: proven topk (4 rows).
// Block-uniform branch; 1280 blocks co-resident (5/CU at 18.9KB LDS). Saves one
// ~15-22us launch slot vs R5 without R10's per-block device-fence catastrophe.
__global__ __launch_bounds__(256) void tp_kernel(
    const __half* __restrict__ Ah, const __half* __restrict__ Bh,
    const float* __restrict__ W2, const float* __restrict__ b2,
    float* __restrict__ out)
{
    __shared__ __align__(16) __half AsH[32 * HP];
    __shared__ __align__(16) __half BsH[32 * HP];
    __shared__ __align__(16) __half2 Wh[2][68];
    const int tid = threadIdx.x;

    if (blockIdx.x >= 1024) {
        // ================= topk (proven round 5) =================
        const int lane = tid & 63;
        const int row  = (blockIdx.x - 1024) * 4 + (tid >> 6);
        float* sr = out + (size_t)row * N;

        float v[16];
#pragma unroll
        for (int c = 0; c < 4; ++c) {
            const float4 f = *(const float4*)&sr[(c * 64 + lane) * 4];
            v[c * 4 + 0] = f.x; v[c * 4 + 1] = f.y; v[c * 4 + 2] = f.z; v[c * 4 + 3] = f.w;
        }
        float m = v[0];
#pragma unroll
        for (int e = 1; e < 16; ++e) m = fmaxf(m, v[e]);
#pragma unroll
        for (int off = 1; off < 64; off <<= 1) m = fmaxf(m, __shfl_xor(m, off));
        float sum = 0.f;
#pragma unroll
        for (int e = 0; e < 16; ++e) sum += __expf(v[e] - m);
#pragma unroll
        for (int off = 1; off < 64; off <<= 1) sum += __shfl_xor(sum, off);
        const float inv = 1.0f / sum;

        unsigned key[16];
#pragma unroll
        for (int e = 0; e < 16; ++e) {
            const int j = (((e >> 2) * 64 + lane) * 4) + (e & 3);
            unsigned u = __float_as_uint(v[e]);
            u = (u & 0x80000000u) ? ~u : (u | 0x80000000u);
            key[e] = (u & 0xFFFFFC00u) | (unsigned)(N - 1 - j);
        }
        unsigned flags = 0;
        for (int it = 0; it < 32; ++it) {
            unsigned best = key[0];
#pragma unroll
            for (int e = 1; e < 16; ++e) best = (key[e] > best) ? key[e] : best;
#pragma unroll
            for (int off = 1; off < 64; off <<= 1) {
                const unsigned o = __shfl_xor(best, off);
                if (o > best) best = o;
            }
#pragma unroll
            for (int e = 0; e < 16; ++e)
                if (key[e] == best) { flags |= 1u << e; key[e] = 0u; }
        }
#pragma unroll
        for (int c = 0; c < 4; ++c) {
            float4 o;
            o.x = (flags & (1u << (c * 4 + 0))) ? __expf(v[c * 4 + 0] - m) * inv : 0.f;
            o.y = (flags & (1u << (c * 4 + 1))) ? __expf(v[c * 4 + 1] - m) * inv : 0.f;
            o.z = (flags & (1u << (c * 4 + 2))) ? __expf(v[c * 4 + 2] - m) * inv : 0.f;
            o.w = (flags & (1u << (c * 4 + 3))) ? __expf(v[c * 4 + 3] - m) * inv : 0.f;
            *(float4*)&sr[(c * 64 + lane) * 4] = o;
        }
        return;
    }

    // ================= pair tile (proven round 5) =================
    const int bi = (blockIdx.x >> 5) * 32, bj = (blockIdx.x & 31) * 32;
    const int tx = tid & 15, ty = tid >> 4;
    float* pout = out + (size_t)N * N;

#pragma unroll
    for (int t = 0; t < 2; ++t) {
        const int e = t * 256 + tid;
        const int row = e >> 4, c = e & 15;
        *(uint4*)&AsH[row * HP + c * 8] = *(const uint4*)&Ah[(size_t)(bi + row) * D + c * 8];
        *(uint4*)&BsH[row * HP + c * 8] = *(const uint4*)&Bh[(size_t)(bj + row) * D + c * 8];
    }
    // Wh[cls][dp] = {W2[2dp][cls]-W2[2dp][2], W2[2dp+1][cls]-W2[2dp+1][2]}  (no 0.5!)
    if (tid < 128) {
        const int cls = tid >> 6, dp = tid & 63;
        Wh[cls][dp] = __floats2half2_rn(W2[6 * dp + cls]     - W2[6 * dp + 2],
                                        W2[6 * dp + 3 + cls] - W2[6 * dp + 5]);
    }
    const float bb0 = b2[0] - b2[2], bb1 = b2[1] - b2[2];
    __syncthreads();

    float acc[4][2];                    // [site=ii*2+jj][class 0,1]; class-2 logit == 0
#pragma unroll
    for (int p = 0; p < 4; ++p) { acc[p][0] = bb0; acc[p][1] = bb1; }

    const __half2 C3  = __float2half2_rn(-0.1029434f);
    const __half2 C1  = __float2half2_rn(-2.3022082f);
    const __half2 ONE = __float2half2_rn(1.0f);

#pragma unroll 4
    for (int c = 0; c < 16; ++c) {      // 16 chunks x 8 d
        H2x4 a0, a1, b0, b1, w0, w1;
        a0.u = *(const uint4*)&AsH[ty * HP + c * 8];
        a1.u = *(const uint4*)&AsH[(ty + 16) * HP + c * 8];
        b0.u = *(const uint4*)&BsH[tx * HP + c * 8];
        b1.u = *(const uint4*)&BsH[(tx + 16) * HP + c * 8];
        w0.u = *(const uint4*)&Wh[0][c * 4];    // wave-uniform -> LDS broadcast
        w1.u = *(const uint4*)&Wh[1][c * 4];
#pragma unroll
        for (int dp = 0; dp < 4; ++dp) {
            const __half2 aa[2] = { a0.h[dp], a1.h[dp] };
            const __half2 bb[2] = { b0.h[dp], b1.h[dp] };
            const __half2 wc0 = w0.h[dp], wc1 = w1.h[dp];
#pragma unroll
            for (int ii = 0; ii < 2; ++ii)
#pragma unroll
                for (int jj = 0; jj < 2; ++jj) {
                    const __half2 x = __hadd2(aa[ii], bb[jj]);
                    const __half2 u = __hmul2(x, x);
                    const __half2 p = __hfma2(C3, u, C1);
                    const __half2 t = __hmul2(x, p);
                    const __half2 e = h2exp2(t);          // 2^t ; under/overflow -> 0/inf (correct limits)
                    const __half2 dn = __hadd2(e, ONE);
                    const __half2 r = h2rcp(dn);          // rcp(inf)=0 -> g=0 (correct)
                    const __half2 g = __hmul2(x, r);      // g = gelu(x)
                    float* l = acc[ii * 2 + jj];
                    l[0] = fdot2_acc(g, wc0, l[0]);
                    l[1] = fdot2_acc(g, wc1, l[1]);
                }
        }
    }

#pragma unroll
    for (int ii = 0; ii < 2; ++ii)
#pragma unroll
        for (int jj = 0; jj < 2; ++jj) {
            const int i = bi + ty + 16 * ii;
            const int j = bj + tx + 16 * jj;
            const float* l = acc[ii * 2 + jj];
            const float l0 = l[0], l1 = l[1];                // l2 == 0
            const float mm = fmaxf(fmaxf(l0, l1), 0.f);
            const float e0 = __expf(l0 - mm), e1 = __expf(l1 - mm), e2 = __expf(-mm);
            const float inv2 = 1.0f / (e0 + e1 + e2);
            float* o = pout + ((size_t)i * N + j) * 3;
            o[0] = e0 * inv2; o[1] = e1 * inv2; o[2] = e2 * inv2;
        }
}

extern "C" void kernel_launch(void* const* d_in, const int* in_sizes, int n_in,
                              void* d_out, int out_size, void* d_ws, size_t ws_size,
                              hipStream_t stream)
{
    const float* z    = (const float*)d_in[0];
    const float* dist = (const float*)d_in[1];
    const float* Wq   = (const float*)d_in[2];
    const float* bq   = (const float*)d_in[3];
    const float* Wk   = (const float*)d_in[4];
    const float* bk   = (const float*)d_in[5];
    const float* W1   = (const float*)d_in[6];
    const float* b1   = (const float*)d_in[7];
    const float* W2   = (const float*)d_in[8];
    const float* b2   = (const float*)d_in[9];

    float* out = (float*)d_out;
    __half* Qh = (__half*)d_ws;
    __half* Kh = Qh + (size_t)N * D;
    __half* Ah = Kh + (size_t)N * D;
    __half* Bh = Ah + (size_t)N * D;

    proj_kernel<<<N / 4, 256, 0, stream>>>(z, Wq, bq, Wk, bk, W1, b1, Qh, Kh, Ah, Bh);
    score_kernel<<<dim3(N / 32, N / 32), 256, 0, stream>>>(Qh, Kh, dist, out);
    tp_kernel<<<1280, 256, 0, stream>>>(Ah, Bh, W2, b2, out);
}

// Round 12
// 134.613 us; speedup vs baseline: 2.6092x; 1.0310x over previous
//
#include <hip/hip_runtime.h>
#include <hip/hip_fp16.h>

#define N 1024
#define D 128

// ---------------- proj v1 (round-5 proven): Qh,Kh,Ah,Bh (f16) = z@{Wq,Wk,W1a,W1b} ----------------
__global__ __launch_bounds__(256) void proj_kernel(
    const float* __restrict__ z,
    const float* __restrict__ Wq, const float* __restrict__ bq,
    const float* __restrict__ Wk, const float* __restrict__ bk,
    const float* __restrict__ W1, const float* __restrict__ b1,
    __half* __restrict__ Qh, __half* __restrict__ Kh,
    __half* __restrict__ Ah, __half* __restrict__ Bh)
{
    const int d  = threadIdx.x & (D - 1);
    const int h  = threadIdx.x >> 7;              // wave-uniform: 0 -> Q/K, 1 -> A/B
    const int r0 = blockIdx.x * 4;
    const float* __restrict__ Wa = h ? W1           : Wq;
    const float* __restrict__ Wb = h ? (W1 + D * D) : Wk;

    float acc0[4] = {0,0,0,0};
    float acc1[4] = {0,0,0,0};

    for (int c = 0; c < D / 4; ++c) {
        float4 zr[4];
#pragma unroll
        for (int r = 0; r < 4; ++r)
            zr[r] = *(const float4*)&z[(r0 + r) * D + c * 4];
#pragma unroll
        for (int q = 0; q < 4; ++q) {
            const int k = c * 4 + q;
            const float wa = Wa[k * D + d];
            const float wb = Wb[k * D + d];
#pragma unroll
            for (int r = 0; r < 4; ++r) {
                const float zv = (q == 0) ? zr[r].x : (q == 1) ? zr[r].y : (q == 2) ? zr[r].z : zr[r].w;
                acc0[r] = fmaf(zv, wa, acc0[r]);
                acc1[r] = fmaf(zv, wb, acc1[r]);
            }
        }
    }
    if (h == 0) {
        const float c0 = bq[d], c1 = bk[d];
        const float scale = 0.08838834764831845f;   // 1/sqrt(128), folded into Qh
#pragma unroll
        for (int r = 0; r < 4; ++r) {
            Qh[(r0 + r) * D + d] = __float2half((acc0[r] + c0) * scale);
            Kh[(r0 + r) * D + d] = __float2half(acc1[r] + c1);
        }
    } else {
        const float c0 = b1[d];
#pragma unroll
        for (int r = 0; r < 4; ++r) {
            Ah[(r0 + r) * D + d] = __float2half(acc0[r] + c0);   // b1 folded
            Bh[(r0 + r) * D + d] = __float2half(acc1[r]);
        }
    }
}

union H2x4 { uint4 u; __half2 h[4]; };

__device__ __forceinline__ float fdot2_acc(__half2 a, __half2 b, float c) {
#if __has_builtin(__builtin_amdgcn_fdot2)
    typedef _Float16 v2h __attribute__((ext_vector_type(2)));
    union { __half2 h; v2h v; } ua, ub;
    ua.h = a; ub.h = b;
    return __builtin_amdgcn_fdot2(ua.v, ub.v, c, false);
#else
    return fmaf(__low2float(a), __low2float(b),
           fmaf(__high2float(a), __high2float(b), c));
#endif
}

#define HP 136   // halves pitch: 272 B rows (16B-aligned); 2-way bank alias only (free)

// ---------------- scores: S = (Qh Kh^T) * exp(-dist), f16 fdot2 (proven round 5) ----------------
__global__ __launch_bounds__(256) void score_kernel(
    const __half* __restrict__ Qh, const __half* __restrict__ Kh,
    const float* __restrict__ dist, float* __restrict__ S)
{
    __shared__ __align__(16) __half Qs[32 * HP];
    __shared__ __align__(16) __half Ks[32 * HP];
    const int tid = threadIdx.x;
    const int bi = blockIdx.y * 32, bj = blockIdx.x * 32;
    const int tx = tid & 15, ty = tid >> 4;

#pragma unroll
    for (int t = 0; t < 2; ++t) {
        const int e = t * 256 + tid;
        const int row = e >> 4, c = e & 15;
        *(uint4*)&Qs[row * HP + c * 8] = *(const uint4*)&Qh[(size_t)(bi + row) * D + c * 8];
        *(uint4*)&Ks[row * HP + c * 8] = *(const uint4*)&Kh[(size_t)(bj + row) * D + c * 8];
    }
    __syncthreads();

    float a00 = 0.f, a01 = 0.f, a10 = 0.f, a11 = 0.f;

#pragma unroll 4
    for (int c = 0; c < 16; ++c) {      // 16 chunks x 8 dims
        H2x4 q0, q1, k0, k1;
        q0.u = *(const uint4*)&Qs[ty * HP + c * 8];
        q1.u = *(const uint4*)&Qs[(ty + 16) * HP + c * 8];
        k0.u = *(const uint4*)&Ks[tx * HP + c * 8];
        k1.u = *(const uint4*)&Ks[(tx + 16) * HP + c * 8];
#pragma unroll
        for (int dp = 0; dp < 4; ++dp) {
            a00 = fdot2_acc(q0.h[dp], k0.h[dp], a00);
            a01 = fdot2_acc(q0.h[dp], k1.h[dp], a01);
            a10 = fdot2_acc(q1.h[dp], k0.h[dp], a10);
            a11 = fdot2_acc(q1.h[dp], k1.h[dp], a11);
        }
    }

    const int i0 = bi + ty, i1 = bi + ty + 16;
    const int j0 = bj + tx, j1 = bj + tx + 16;
    S[(size_t)i0 * N + j0] = a00 * __expf(-dist[(size_t)i0 * N + j0]);
    S[(size_t)i0 * N + j1] = a01 * __expf(-dist[(size_t)i0 * N + j1]);
    S[(size_t)i1 * N + j0] = a10 * __expf(-dist[(size_t)i1 * N + j0]);
    S[(size_t)i1 * N + j1] = a11 * __expf(-dist[(size_t)i1 * N + j1]);
}

// ---------------- fused topk | pair: one dispatch, NO fences ----------------
// Both depend only on PREVIOUS dispatches (topk<-score, pair<-proj): kernel boundary
// provides all visibility. R12 change: topk blocks FIRST (bid<256) so they launch
// early and hide under pair's 43us wall; R11 had them last -> ~9us serial tail.
__global__ __launch_bounds__(256) void tp_kernel(
    const __half* __restrict__ Ah, const __half* __restrict__ Bh,
    const float* __restrict__ W2, const float* __restrict__ b2,
    float* __restrict__ out)
{
    __shared__ __align__(16) __half AsH[32 * HP];
    __shared__ __align__(16) __half BsH[32 * HP];
    __shared__ __align__(16) __half2 Wh[2][68];
    const int tid = threadIdx.x;

    if (blockIdx.x < 256) {
        // ================= topk (proven round 5; launches first, hides under pair) =================
        const int lane = tid & 63;
        const int row  = blockIdx.x * 4 + (tid >> 6);
        float* sr = out + (size_t)row * N;

        float v[16];
#pragma unroll
        for (int c = 0; c < 4; ++c) {
            const float4 f = *(const float4*)&sr[(c * 64 + lane) * 4];
            v[c * 4 + 0] = f.x; v[c * 4 + 1] = f.y; v[c * 4 + 2] = f.z; v[c * 4 + 3] = f.w;
        }
        float m = v[0];
#pragma unroll
        for (int e = 1; e < 16; ++e) m = fmaxf(m, v[e]);
#pragma unroll
        for (int off = 1; off < 64; off <<= 1) m = fmaxf(m, __shfl_xor(m, off));
        float sum = 0.f;
#pragma unroll
        for (int e = 0; e < 16; ++e) sum += __expf(v[e] - m);
#pragma unroll
        for (int off = 1; off < 64; off <<= 1) sum += __shfl_xor(sum, off);
        const float inv = 1.0f / sum;

        unsigned key[16];
#pragma unroll
        for (int e = 0; e < 16; ++e) {
            const int j = (((e >> 2) * 64 + lane) * 4) + (e & 3);
            unsigned u = __float_as_uint(v[e]);
            u = (u & 0x80000000u) ? ~u : (u | 0x80000000u);
            key[e] = (u & 0xFFFFFC00u) | (unsigned)(N - 1 - j);
        }
        unsigned flags = 0;
        for (int it = 0; it < 32; ++it) {
            unsigned best = key[0];
#pragma unroll
            for (int e = 1; e < 16; ++e) best = (key[e] > best) ? key[e] : best;
#pragma unroll
            for (int off = 1; off < 64; off <<= 1) {
                const unsigned o = __shfl_xor(best, off);
                if (o > best) best = o;
            }
#pragma unroll
            for (int e = 0; e < 16; ++e)
                if (key[e] == best) { flags |= 1u << e; key[e] = 0u; }
        }
#pragma unroll
        for (int c = 0; c < 4; ++c) {
            float4 o;
            o.x = (flags & (1u << (c * 4 + 0))) ? __expf(v[c * 4 + 0] - m) * inv : 0.f;
            o.y = (flags & (1u << (c * 4 + 1))) ? __expf(v[c * 4 + 1] - m) * inv : 0.f;
            o.z = (flags & (1u << (c * 4 + 2))) ? __expf(v[c * 4 + 2] - m) * inv : 0.f;
            o.w = (flags & (1u << (c * 4 + 3))) ? __expf(v[c * 4 + 3] - m) * inv : 0.f;
            *(float4*)&sr[(c * 64 + lane) * 4] = o;
        }
        return;
    }

    // ================= pair tile (proven round 5) =================
    const int pb = blockIdx.x - 256;
    const int bi = (pb >> 5) * 32, bj = (pb & 31) * 32;
    const int tx = tid & 15, ty = tid >> 4;
    float* pout = out + (size_t)N * N;

#pragma unroll
    for (int t = 0; t < 2; ++t) {
        const int e = t * 256 + tid;
        const int row = e >> 4, c = e & 15;
        *(uint4*)&AsH[row * HP + c * 8] = *(const uint4*)&Ah[(size_t)(bi + row) * D + c * 8];
        *(uint4*)&BsH[row * HP + c * 8] = *(const uint4*)&Bh[(size_t)(bj + row) * D + c * 8];
    }
    // Wh[cls][dp] = {W2[2dp][cls]-W2[2dp][2], W2[2dp+1][cls]-W2[2dp+1][2]}  (no 0.5!)
    if (tid < 128) {
        const int cls = tid >> 6, dp = tid & 63;
        Wh[cls][dp] = __floats2half2_rn(W2[6 * dp + cls]     - W2[6 * dp + 2],
                                        W2[6 * dp + 3 + cls] - W2[6 * dp + 5]);
    }
    const float bb0 = b2[0] - b2[2], bb1 = b2[1] - b2[2];
    __syncthreads();

    float acc[4][2];                    // [site=ii*2+jj][class 0,1]; class-2 logit == 0
#pragma unroll
    for (int p = 0; p < 4; ++p) { acc[p][0] = bb0; acc[p][1] = bb1; }

    const __half2 C3  = __float2half2_rn(-0.1029434f);
    const __half2 C1  = __float2half2_rn(-2.3022082f);
    const __half2 ONE = __float2half2_rn(1.0f);

#pragma unroll 4
    for (int c = 0; c < 16; ++c) {      // 16 chunks x 8 d
        H2x4 a0, a1, b0, b1, w0, w1;
        a0.u = *(const uint4*)&AsH[ty * HP + c * 8];
        a1.u = *(const uint4*)&AsH[(ty + 16) * HP + c * 8];
        b0.u = *(const uint4*)&BsH[tx * HP + c * 8];
        b1.u = *(const uint4*)&BsH[(tx + 16) * HP + c * 8];
        w0.u = *(const uint4*)&Wh[0][c * 4];    // wave-uniform -> LDS broadcast
        w1.u = *(const uint4*)&Wh[1][c * 4];
#pragma unroll
        for (int dp = 0; dp < 4; ++dp) {
            const __half2 aa[2] = { a0.h[dp], a1.h[dp] };
            const __half2 bb[2] = { b0.h[dp], b1.h[dp] };
            const __half2 wc0 = w0.h[dp], wc1 = w1.h[dp];
#pragma unroll
            for (int ii = 0; ii < 2; ++ii)
#pragma unroll
                for (int jj = 0; jj < 2; ++jj) {
                    const __half2 x = __hadd2(aa[ii], bb[jj]);
                    const __half2 u = __hmul2(x, x);
                    const __half2 p = __hfma2(C3, u, C1);
                    const __half2 t = __hmul2(x, p);
                    const __half2 e = h2exp2(t);          // 2^t ; under/overflow -> 0/inf (correct limits)
                    const __half2 dn = __hadd2(e, ONE);
                    const __half2 r = h2rcp(dn);          // rcp(inf)=0 -> g=0 (correct)
                    const __half2 g = __hmul2(x, r);      // g = gelu(x)
                    float* l = acc[ii * 2 + jj];
                    l[0] = fdot2_acc(g, wc0, l[0]);
                    l[1] = fdot2_acc(g, wc1, l[1]);
                }
        }
    }

#pragma unroll
    for (int ii = 0; ii < 2; ++ii)
#pragma unroll
        for (int jj = 0; jj < 2; ++jj) {
            const int i = bi + ty + 16 * ii;
            const int j = bj + tx + 16 * jj;
            const float* l = acc[ii * 2 + jj];
            const float l0 = l[0], l1 = l[1];                // l2 == 0
            const float mm = fmaxf(fmaxf(l0, l1), 0.f);
            const float e0 = __expf(l0 - mm), e1 = __expf(l1 - mm), e2 = __expf(-mm);
            const float inv2 = 1.0f / (e0 + e1 + e2);
            float* o = pout + ((size_t)i * N + j) * 3;
            o[0] = e0 * inv2; o[1] = e1 * inv2; o[2] = e2 * inv2;
        }
}

extern "C" void kernel_launch(void* const* d_in, const int* in_sizes, int n_in,
                              void* d_out, int out_size, void* d_ws, size_t ws_size,
                              hipStream_t stream)
{
    const float* z    = (const float*)d_in[0];
    const float* dist = (const float*)d_in[1];
    const float* Wq   = (const float*)d_in[2];
    const float* bq   = (const float*)d_in[3];
    const float* Wk   = (const float*)d_in[4];
    const float* bk   = (const float*)d_in[5];
    const float* W1   = (const float*)d_in[6];
    const float* b1   = (const float*)d_in[7];
    const float* W2   = (const float*)d_in[8];
    const float* b2   = (const float*)d_in[9];

    float* out = (float*)d_out;
    __half* Qh = (__half*)d_ws;
    __half* Kh = Qh + (size_t)N * D;
    __half* Ah = Kh + (size_t)N * D;
    __half* Bh = Ah + (size_t)N * D;

    proj_kernel<<<N / 4, 256, 0, stream>>>(z, Wq, bq, Wk, bk, W1, b1, Qh, Kh, Ah, Bh);
    score_kernel<<<dim3(N / 32, N / 32), 256, 0, stream>>>(Qh, Kh, dist, out);
    tp_kernel<<<1280, 256, 0, stream>>>(Ah, Bh, W2, b2, out);
}

// Round 13
// 129.645 us; speedup vs baseline: 2.7092x; 1.0383x over previous
//
#include <hip/hip_runtime.h>
#include <hip/hip_fp16.h>

#define N 1024
#define D 128

// ---------------- proj v1 (round-5 proven): Qh,Kh,Ah,Bh (f16) = z@{Wq,Wk,W1a,W1b} ----------------
__global__ __launch_bounds__(256) void proj_kernel(
    const float* __restrict__ z,
    const float* __restrict__ Wq, const float* __restrict__ bq,
    const float* __restrict__ Wk, const float* __restrict__ bk,
    const float* __restrict__ W1, const float* __restrict__ b1,
    __half* __restrict__ Qh, __half* __restrict__ Kh,
    __half* __restrict__ Ah, __half* __restrict__ Bh)
{
    const int d  = threadIdx.x & (D - 1);
    const int h  = threadIdx.x >> 7;              // wave-uniform: 0 -> Q/K, 1 -> A/B
    const int r0 = blockIdx.x * 4;
    const float* __restrict__ Wa = h ? W1           : Wq;
    const float* __restrict__ Wb = h ? (W1 + D * D) : Wk;

    float acc0[4] = {0,0,0,0};
    float acc1[4] = {0,0,0,0};

    for (int c = 0; c < D / 4; ++c) {
        float4 zr[4];
#pragma unroll
        for (int r = 0; r < 4; ++r)
            zr[r] = *(const float4*)&z[(r0 + r) * D + c * 4];
#pragma unroll
        for (int q = 0; q < 4; ++q) {
            const int k = c * 4 + q;
            const float wa = Wa[k * D + d];
            const float wb = Wb[k * D + d];
#pragma unroll
            for (int r = 0; r < 4; ++r) {
                const float zv = (q == 0) ? zr[r].x : (q == 1) ? zr[r].y : (q == 2) ? zr[r].z : zr[r].w;
                acc0[r] = fmaf(zv, wa, acc0[r]);
                acc1[r] = fmaf(zv, wb, acc1[r]);
            }
        }
    }
    if (h == 0) {
        const float c0 = bq[d], c1 = bk[d];
        const float scale = 0.08838834764831845f;   // 1/sqrt(128), folded into Qh
#pragma unroll
        for (int r = 0; r < 4; ++r) {
            Qh[(r0 + r) * D + d] = __float2half((acc0[r] + c0) * scale);
            Kh[(r0 + r) * D + d] = __float2half(acc1[r] + c1);
        }
    } else {
        const float c0 = b1[d];
#pragma unroll
        for (int r = 0; r < 4; ++r) {
            Ah[(r0 + r) * D + d] = __float2half(acc0[r] + c0);   // b1 folded
            Bh[(r0 + r) * D + d] = __float2half(acc1[r]);
        }
    }
}

union H2x4 { uint4 u; __half2 h[4]; };

__device__ __forceinline__ float fdot2_acc(__half2 a, __half2 b, float c) {
#if __has_builtin(__builtin_amdgcn_fdot2)
    typedef _Float16 v2h __attribute__((ext_vector_type(2)));
    union { __half2 h; v2h v; } ua, ub;
    ua.h = a; ub.h = b;
    return __builtin_amdgcn_fdot2(ua.v, ub.v, c, false);
#else
    return fmaf(__low2float(a), __low2float(b),
           fmaf(__high2float(a), __high2float(b), c));
#endif
}

#define HP 136   // halves pitch: 272 B rows (16B-aligned); 2-way bank alias only (free)

// ---------------- scores: S = (Qh Kh^T) * exp(-dist), f16 fdot2 (proven round 5) ----------------
__global__ __launch_bounds__(256) void score_kernel(
    const __half* __restrict__ Qh, const __half* __restrict__ Kh,
    const float* __restrict__ dist, float* __restrict__ S)
{
    __shared__ __align__(16) __half Qs[32 * HP];
    __shared__ __align__(16) __half Ks[32 * HP];
    const int tid = threadIdx.x;
    const int bi = blockIdx.y * 32, bj = blockIdx.x * 32;
    const int tx = tid & 15, ty = tid >> 4;

#pragma unroll
    for (int t = 0; t < 2; ++t) {
        const int e = t * 256 + tid;
        const int row = e >> 4, c = e & 15;
        *(uint4*)&Qs[row * HP + c * 8] = *(const uint4*)&Qh[(size_t)(bi + row) * D + c * 8];
        *(uint4*)&Ks[row * HP + c * 8] = *(const uint4*)&Kh[(size_t)(bj + row) * D + c * 8];
    }
    __syncthreads();

    float a00 = 0.f, a01 = 0.f, a10 = 0.f, a11 = 0.f;

#pragma unroll 4
    for (int c = 0; c < 16; ++c) {      // 16 chunks x 8 dims
        H2x4 q0, q1, k0, k1;
        q0.u = *(const uint4*)&Qs[ty * HP + c * 8];
        q1.u = *(const uint4*)&Qs[(ty + 16) * HP + c * 8];
        k0.u = *(const uint4*)&Ks[tx * HP + c * 8];
        k1.u = *(const uint4*)&Ks[(tx + 16) * HP + c * 8];
#pragma unroll
        for (int dp = 0; dp < 4; ++dp) {
            a00 = fdot2_acc(q0.h[dp], k0.h[dp], a00);
            a01 = fdot2_acc(q0.h[dp], k1.h[dp], a01);
            a10 = fdot2_acc(q1.h[dp], k0.h[dp], a10);
            a11 = fdot2_acc(q1.h[dp], k1.h[dp], a11);
        }
    }

    const int i0 = bi + ty, i1 = bi + ty + 16;
    const int j0 = bj + tx, j1 = bj + tx + 16;
    S[(size_t)i0 * N + j0] = a00 * __expf(-dist[(size_t)i0 * N + j0]);
    S[(size_t)i0 * N + j1] = a01 * __expf(-dist[(size_t)i0 * N + j1]);
    S[(size_t)i1 * N + j0] = a10 * __expf(-dist[(size_t)i1 * N + j0]);
    S[(size_t)i1 * N + j1] = a11 * __expf(-dist[(size_t)i1 * N + j1]);
}

// ---------------- fused topk | pair: one dispatch, NO fences (proven round 12) ----------------
// topk blocks FIRST (bid<256): launch early, hide under pair's wall (R12: tp 52.3->47.3).
// R13 change: sigmoid-form gelu x*sigma(1.702x) = x/(1+2^(-2.45547x)) -- 3 pk + 4 trans + 2 dot
// issue slots vs tanh-form's 6+4+2 (uniform-issue model fitted from the R0/R2 null).
// Error budget: |gelu err| <= 0.021 elementwise -> logit rms ~0.008 -> output ~0.005;
// stacked on f16 base 0.0039 => expect absmax 0.006-0.012 < 0.0192 threshold.
__global__ __launch_bounds__(256) void tp_kernel(
    const __half* __restrict__ Ah, const __half* __restrict__ Bh,
    const float* __restrict__ W2, const float* __restrict__ b2,
    float* __restrict__ out)
{
    __shared__ __align__(16) __half AsH[32 * HP];
    __shared__ __align__(16) __half BsH[32 * HP];
    __shared__ __align__(16) __half2 Wh[2][68];
    const int tid = threadIdx.x;

    if (blockIdx.x < 256) {
        // ================= topk (proven round 5; launches first, hides under pair) =================
        const int lane = tid & 63;
        const int row  = blockIdx.x * 4 + (tid >> 6);
        float* sr = out + (size_t)row * N;

        float v[16];
#pragma unroll
        for (int c = 0; c < 4; ++c) {
            const float4 f = *(const float4*)&sr[(c * 64 + lane) * 4];
            v[c * 4 + 0] = f.x; v[c * 4 + 1] = f.y; v[c * 4 + 2] = f.z; v[c * 4 + 3] = f.w;
        }
        float m = v[0];
#pragma unroll
        for (int e = 1; e < 16; ++e) m = fmaxf(m, v[e]);
#pragma unroll
        for (int off = 1; off < 64; off <<= 1) m = fmaxf(m, __shfl_xor(m, off));
        float sum = 0.f;
#pragma unroll
        for (int e = 0; e < 16; ++e) sum += __expf(v[e] - m);
#pragma unroll
        for (int off = 1; off < 64; off <<= 1) sum += __shfl_xor(sum, off);
        const float inv = 1.0f / sum;

        unsigned key[16];
#pragma unroll
        for (int e = 0; e < 16; ++e) {
            const int j = (((e >> 2) * 64 + lane) * 4) + (e & 3);
            unsigned u = __float_as_uint(v[e]);
            u = (u & 0x80000000u) ? ~u : (u | 0x80000000u);
            key[e] = (u & 0xFFFFFC00u) | (unsigned)(N - 1 - j);
        }
        unsigned flags = 0;
        for (int it = 0; it < 32; ++it) {
            unsigned best = key[0];
#pragma unroll
            for (int e = 1; e < 16; ++e) best = (key[e] > best) ? key[e] : best;
#pragma unroll
            for (int off = 1; off < 64; off <<= 1) {
                const unsigned o = __shfl_xor(best, off);
                if (o > best) best = o;
            }
#pragma unroll
            for (int e = 0; e < 16; ++e)
                if (key[e] == best) { flags |= 1u << e; key[e] = 0u; }
        }
#pragma unroll
        for (int c = 0; c < 4; ++c) {
            float4 o;
            o.x = (flags & (1u << (c * 4 + 0))) ? __expf(v[c * 4 + 0] - m) * inv : 0.f;
            o.y = (flags & (1u << (c * 4 + 1))) ? __expf(v[c * 4 + 1] - m) * inv : 0.f;
            o.z = (flags & (1u << (c * 4 + 2))) ? __expf(v[c * 4 + 2] - m) * inv : 0.f;
            o.w = (flags & (1u << (c * 4 + 3))) ? __expf(v[c * 4 + 3] - m) * inv : 0.f;
            *(float4*)&sr[(c * 64 + lane) * 4] = o;
        }
        return;
    }

    // ================= pair tile (round 12 structure, sigmoid-form gelu) =================
    const int pb = blockIdx.x - 256;
    const int bi = (pb >> 5) * 32, bj = (pb & 31) * 32;
    const int tx = tid & 15, ty = tid >> 4;
    float* pout = out + (size_t)N * N;

#pragma unroll
    for (int t = 0; t < 2; ++t) {
        const int e = t * 256 + tid;
        const int row = e >> 4, c = e & 15;
        *(uint4*)&AsH[row * HP + c * 8] = *(const uint4*)&Ah[(size_t)(bi + row) * D + c * 8];
        *(uint4*)&BsH[row * HP + c * 8] = *(const uint4*)&Bh[(size_t)(bj + row) * D + c * 8];
    }
    // Wh[cls][dp] = {W2[2dp][cls]-W2[2dp][2], W2[2dp+1][cls]-W2[2dp+1][2]}  (no 0.5!)
    if (tid < 128) {
        const int cls = tid >> 6, dp = tid & 63;
        Wh[cls][dp] = __floats2half2_rn(W2[6 * dp + cls]     - W2[6 * dp + 2],
                                        W2[6 * dp + 3 + cls] - W2[6 * dp + 5]);
    }
    const float bb0 = b2[0] - b2[2], bb1 = b2[1] - b2[2];
    __syncthreads();

    float acc[4][2];                    // [site=ii*2+jj][class 0,1]; class-2 logit == 0
#pragma unroll
    for (int p = 0; p < 4; ++p) { acc[p][0] = bb0; acc[p][1] = bb1; }

    const __half2 CS  = __float2half2_rn(-2.45547f);   // -1.702/ln(2)
    const __half2 ONE = __float2half2_rn(1.0f);

#pragma unroll 4
    for (int c = 0; c < 16; ++c) {      // 16 chunks x 8 d
        H2x4 a0, a1, b0, b1, w0, w1;
        a0.u = *(const uint4*)&AsH[ty * HP + c * 8];
        a1.u = *(const uint4*)&AsH[(ty + 16) * HP + c * 8];
        b0.u = *(const uint4*)&BsH[tx * HP + c * 8];
        b1.u = *(const uint4*)&BsH[(tx + 16) * HP + c * 8];
        w0.u = *(const uint4*)&Wh[0][c * 4];    // wave-uniform -> LDS broadcast
        w1.u = *(const uint4*)&Wh[1][c * 4];
#pragma unroll
        for (int dp = 0; dp < 4; ++dp) {
            const __half2 aa[2] = { a0.h[dp], a1.h[dp] };
            const __half2 bb[2] = { b0.h[dp], b1.h[dp] };
            const __half2 wc0 = w0.h[dp], wc1 = w1.h[dp];
#pragma unroll
            for (int ii = 0; ii < 2; ++ii)
#pragma unroll
                for (int jj = 0; jj < 2; ++jj) {
                    const __half2 x  = __hadd2(aa[ii], bb[jj]);
                    const __half2 t  = __hmul2(x, CS);    // -2.45547*x
                    const __half2 e  = h2exp2(t);         // 2^t; overflow->inf, underflow->0
                    const __half2 dn = __hadd2(e, ONE);
                    const __half2 r  = h2rcp(dn);         // rcp(inf)=0 -> g=0 (x->-inf limit ok)
                    const __half2 g  = __hmul2(x, r);     // g = x*sigma(1.702x) ~ gelu(x)
                    float* l = acc[ii * 2 + jj];
                    l[0] = fdot2_acc(g, wc0, l[0]);
                    l[1] = fdot2_acc(g, wc1, l[1]);
                }
        }
    }

#pragma unroll
    for (int ii = 0; ii < 2; ++ii)
#pragma unroll
        for (int jj = 0; jj < 2; ++jj) {
            const int i = bi + ty + 16 * ii;
            const int j = bj + tx + 16 * jj;
            const float* l = acc[ii * 2 + jj];
            const float l0 = l[0], l1 = l[1];                // l2 == 0
            const float mm = fmaxf(fmaxf(l0, l1), 0.f);
            const float e0 = __expf(l0 - mm), e1 = __expf(l1 - mm), e2 = __expf(-mm);
            const float inv2 = 1.0f / (e0 + e1 + e2);
            float* o = pout + ((size_t)i * N + j) * 3;
            o[0] = e0 * inv2; o[1] = e1 * inv2; o[2] = e2 * inv2;
        }
}

extern "C" void kernel_launch(void* const* d_in, const int* in_sizes, int n_in,
                              void* d_out, int out_size, void* d_ws, size_t ws_size,
                              hipStream_t stream)
{
    const float* z    = (const float*)d_in[0];
    const float* dist = (const float*)d_in[1];
    const float* Wq   = (const float*)d_in[2];
    const float* bq   = (const float*)d_in[3];
    const float* Wk   = (const float*)d_in[4];
    const float* bk   = (const float*)d_in[5];
    const float* W1   = (const float*)d_in[6];
    const float* b1   = (const float*)d_in[7];
    const float* W2   = (const float*)d_in[8];
    const float* b2   = (const float*)d_in[9];

    float* out = (float*)d_out;
    __half* Qh = (__half*)d_ws;
    __half* Kh = Qh + (size_t)N * D;
    __half* Ah = Kh + (size_t)N * D;
    __half* Bh = Ah + (size_t)N * D;

    proj_kernel<<<N / 4, 256, 0, stream>>>(z, Wq, bq, Wk, bk, W1, b1, Qh, Kh, Ah, Bh);
    score_kernel<<<dim3(N / 32, N / 32), 256, 0, stream>>>(Qh, Kh, dist, out);
    tp_kernel<<<1280, 256, 0, stream>>>(Ah, Bh, W2, b2, out);
}

// Round 14
// 128.441 us; speedup vs baseline: 2.7346x; 1.0094x over previous
//
#include <hip/hip_runtime.h>
#include <hip/hip_fp16.h>

#define N 1024
#define D 128

// ---------------- proj v1 (round-5 proven): Qh,Kh,Ah,Bh (f16) = z@{Wq,Wk,W1a,W1b} ----------------
__global__ __launch_bounds__(256) void proj_kernel(
    const float* __restrict__ z,
    const float* __restrict__ Wq, const float* __restrict__ bq,
    const float* __restrict__ Wk, const float* __restrict__ bk,
    const float* __restrict__ W1, const float* __restrict__ b1,
    __half* __restrict__ Qh, __half* __restrict__ Kh,
    __half* __restrict__ Ah, __half* __restrict__ Bh)
{
    const int d  = threadIdx.x & (D - 1);
    const int h  = threadIdx.x >> 7;              // wave-uniform: 0 -> Q/K, 1 -> A/B
    const int r0 = blockIdx.x * 4;
    const float* __restrict__ Wa = h ? W1           : Wq;
    const float* __restrict__ Wb = h ? (W1 + D * D) : Wk;

    float acc0[4] = {0,0,0,0};
    float acc1[4] = {0,0,0,0};

    for (int c = 0; c < D / 4; ++c) {
        float4 zr[4];
#pragma unroll
        for (int r = 0; r < 4; ++r)
            zr[r] = *(const float4*)&z[(r0 + r) * D + c * 4];
#pragma unroll
        for (int q = 0; q < 4; ++q) {
            const int k = c * 4 + q;
            const float wa = Wa[k * D + d];
            const float wb = Wb[k * D + d];
#pragma unroll
            for (int r = 0; r < 4; ++r) {
                const float zv = (q == 0) ? zr[r].x : (q == 1) ? zr[r].y : (q == 2) ? zr[r].z : zr[r].w;
                acc0[r] = fmaf(zv, wa, acc0[r]);
                acc1[r] = fmaf(zv, wb, acc1[r]);
            }
        }
    }
    if (h == 0) {
        const float c0 = bq[d], c1 = bk[d];
        const float scale = 0.08838834764831845f;   // 1/sqrt(128), folded into Qh
#pragma unroll
        for (int r = 0; r < 4; ++r) {
            Qh[(r0 + r) * D + d] = __float2half((acc0[r] + c0) * scale);
            Kh[(r0 + r) * D + d] = __float2half(acc1[r] + c1);
        }
    } else {
        const float c0 = b1[d];
#pragma unroll
        for (int r = 0; r < 4; ++r) {
            Ah[(r0 + r) * D + d] = __float2half(acc0[r] + c0);   // b1 folded
            Bh[(r0 + r) * D + d] = __float2half(acc1[r]);
        }
    }
}

union H2x4 { uint4 u; __half2 h[4]; };

__device__ __forceinline__ float fdot2_acc(__half2 a, __half2 b, float c) {
#if __has_builtin(__builtin_amdgcn_fdot2)
    typedef _Float16 v2h __attribute__((ext_vector_type(2)));
    union { __half2 h; v2h v; } ua, ub;
    ua.h = a; ub.h = b;
    return __builtin_amdgcn_fdot2(ua.v, ub.v, c, false);
#else
    return fmaf(__low2float(a), __low2float(b),
           fmaf(__high2float(a), __high2float(b), c));
#endif
}

#define HP 136   // halves pitch: 272 B rows (16B-aligned); 2-way bank alias only (free)

// ---------------- scores: S = (Qh Kh^T) * exp(-dist), f16 fdot2 (proven round 5) ----------------
__global__ __launch_bounds__(256) void score_kernel(
    const __half* __restrict__ Qh, const __half* __restrict__ Kh,
    const float* __restrict__ dist, float* __restrict__ S)
{
    __shared__ __align__(16) __half Qs[32 * HP];
    __shared__ __align__(16) __half Ks[32 * HP];
    const int tid = threadIdx.x;
    const int bi = blockIdx.y * 32, bj = blockIdx.x * 32;
    const int tx = tid & 15, ty = tid >> 4;

#pragma unroll
    for (int t = 0; t < 2; ++t) {
        const int e = t * 256 + tid;
        const int row = e >> 4, c = e & 15;
        *(uint4*)&Qs[row * HP + c * 8] = *(const uint4*)&Qh[(size_t)(bi + row) * D + c * 8];
        *(uint4*)&Ks[row * HP + c * 8] = *(const uint4*)&Kh[(size_t)(bj + row) * D + c * 8];
    }
    __syncthreads();

    float a00 = 0.f, a01 = 0.f, a10 = 0.f, a11 = 0.f;

#pragma unroll 4
    for (int c = 0; c < 16; ++c) {      // 16 chunks x 8 dims
        H2x4 q0, q1, k0, k1;
        q0.u = *(const uint4*)&Qs[ty * HP + c * 8];
        q1.u = *(const uint4*)&Qs[(ty + 16) * HP + c * 8];
        k0.u = *(const uint4*)&Ks[tx * HP + c * 8];
        k1.u = *(const uint4*)&Ks[(tx + 16) * HP + c * 8];
#pragma unroll
        for (int dp = 0; dp < 4; ++dp) {
            a00 = fdot2_acc(q0.h[dp], k0.h[dp], a00);
            a01 = fdot2_acc(q0.h[dp], k1.h[dp], a01);
            a10 = fdot2_acc(q1.h[dp], k0.h[dp], a10);
            a11 = fdot2_acc(q1.h[dp], k1.h[dp], a11);
        }
    }

    const int i0 = bi + ty, i1 = bi + ty + 16;
    const int j0 = bj + tx, j1 = bj + tx + 16;
    S[(size_t)i0 * N + j0] = a00 * __expf(-dist[(size_t)i0 * N + j0]);
    S[(size_t)i0 * N + j1] = a01 * __expf(-dist[(size_t)i0 * N + j1]);
    S[(size_t)i1 * N + j0] = a10 * __expf(-dist[(size_t)i1 * N + j0]);
    S[(size_t)i1 * N + j1] = a11 * __expf(-dist[(size_t)i1 * N + j1]);
}

// ---------------- fused topk | pair: one dispatch, NO fences ----------------
// topk blocks FIRST (bid<256): launch early, hide under pair's wall (proven R12).
// R14 change: pair tile 32x32 -> 16x32 (2 sites/thread), 2048 pair blocks.
// R13's grid (1280 blocks) = 5 blocks/CU = 20/32 wave slots -> 13us of stall at 70% VALUBusy.
// 2304 blocks ~ 9/CU vs 8/CU cap (LDS ~14KB) -> 32 waves/CU resident, trans-pipe bubbles
// filled by TLP. Per-site math bit-identical (same op order) -> absmax unchanged.
__global__ __launch_bounds__(256) void tp_kernel(
    const __half* __restrict__ Ah, const __half* __restrict__ Bh,
    const float* __restrict__ W2, const float* __restrict__ b2,
    float* __restrict__ out)
{
    __shared__ __align__(16) __half AsH[16 * HP];
    __shared__ __align__(16) __half BsH[32 * HP];
    __shared__ __align__(16) __half2 Wh[2][68];
    const int tid = threadIdx.x;

    if (blockIdx.x < 256) {
        // ================= topk (proven round 5; launches first, hides under pair) =================
        const int lane = tid & 63;
        const int row  = blockIdx.x * 4 + (tid >> 6);
        float* sr = out + (size_t)row * N;

        float v[16];
#pragma unroll
        for (int c = 0; c < 4; ++c) {
            const float4 f = *(const float4*)&sr[(c * 64 + lane) * 4];
            v[c * 4 + 0] = f.x; v[c * 4 + 1] = f.y; v[c * 4 + 2] = f.z; v[c * 4 + 3] = f.w;
        }
        float m = v[0];
#pragma unroll
        for (int e = 1; e < 16; ++e) m = fmaxf(m, v[e]);
#pragma unroll
        for (int off = 1; off < 64; off <<= 1) m = fmaxf(m, __shfl_xor(m, off));
        float sum = 0.f;
#pragma unroll
        for (int e = 0; e < 16; ++e) sum += __expf(v[e] - m);
#pragma unroll
        for (int off = 1; off < 64; off <<= 1) sum += __shfl_xor(sum, off);
        const float inv = 1.0f / sum;

        unsigned key[16];
#pragma unroll
        for (int e = 0; e < 16; ++e) {
            const int j = (((e >> 2) * 64 + lane) * 4) + (e & 3);
            unsigned u = __float_as_uint(v[e]);
            u = (u & 0x80000000u) ? ~u : (u | 0x80000000u);
            key[e] = (u & 0xFFFFFC00u) | (unsigned)(N - 1 - j);
        }
        unsigned flags = 0;
        for (int it = 0; it < 32; ++it) {
            unsigned best = key[0];
#pragma unroll
            for (int e = 1; e < 16; ++e) best = (key[e] > best) ? key[e] : best;
#pragma unroll
            for (int off = 1; off < 64; off <<= 1) {
                const unsigned o = __shfl_xor(best, off);
                if (o > best) best = o;
            }
#pragma unroll
            for (int e = 0; e < 16; ++e)
                if (key[e] == best) { flags |= 1u << e; key[e] = 0u; }
        }
#pragma unroll
        for (int c = 0; c < 4; ++c) {
            float4 o;
            o.x = (flags & (1u << (c * 4 + 0))) ? __expf(v[c * 4 + 0] - m) * inv : 0.f;
            o.y = (flags & (1u << (c * 4 + 1))) ? __expf(v[c * 4 + 1] - m) * inv : 0.f;
            o.z = (flags & (1u << (c * 4 + 2))) ? __expf(v[c * 4 + 2] - m) * inv : 0.f;
            o.w = (flags & (1u << (c * 4 + 3))) ? __expf(v[c * 4 + 3] - m) * inv : 0.f;
            *(float4*)&sr[(c * 64 + lane) * 4] = o;
        }
        return;
    }

    // ================= pair tile 16x32, 2 sites/thread (sigmoid gelu, R13 math) =================
    const int pb = blockIdx.x - 256;                    // 0..2047
    const int bi = (pb >> 5) * 16, bj = (pb & 31) * 32;
    const int tx = tid & 15, ty = tid >> 4;             // ty: 0..15 (i-row), tx: j and j+16
    float* pout = out + (size_t)N * N;

    // stage A (16 rows): 256 uint4 = 1/thread; B (32 rows): 512 uint4 = 2/thread
    {
        const int row = tid >> 4, c = tid & 15;
        *(uint4*)&AsH[row * HP + c * 8] = *(const uint4*)&Ah[(size_t)(bi + row) * D + c * 8];
    }
#pragma unroll
    for (int t = 0; t < 2; ++t) {
        const int e = t * 256 + tid;
        const int row = e >> 4, c = e & 15;
        *(uint4*)&BsH[row * HP + c * 8] = *(const uint4*)&Bh[(size_t)(bj + row) * D + c * 8];
    }
    // Wh[cls][dp] = {W2[2dp][cls]-W2[2dp][2], W2[2dp+1][cls]-W2[2dp+1][2]}  (no 0.5!)
    if (tid < 128) {
        const int cls = tid >> 6, dp = tid & 63;
        Wh[cls][dp] = __floats2half2_rn(W2[6 * dp + cls]     - W2[6 * dp + 2],
                                        W2[6 * dp + 3 + cls] - W2[6 * dp + 5]);
    }
    const float bb0 = b2[0] - b2[2], bb1 = b2[1] - b2[2];
    __syncthreads();

    float acc[2][2];                    // [site jj][class 0,1]; class-2 logit == 0
#pragma unroll
    for (int p = 0; p < 2; ++p) { acc[p][0] = bb0; acc[p][1] = bb1; }

    const __half2 CS  = __float2half2_rn(-2.45547f);   // -1.702/ln(2)
    const __half2 ONE = __float2half2_rn(1.0f);

#pragma unroll 4
    for (int c = 0; c < 16; ++c) {      // 16 chunks x 8 d
        H2x4 a0, b0, b1, w0, w1;
        a0.u = *(const uint4*)&AsH[ty * HP + c * 8];
        b0.u = *(const uint4*)&BsH[tx * HP + c * 8];
        b1.u = *(const uint4*)&BsH[(tx + 16) * HP + c * 8];
        w0.u = *(const uint4*)&Wh[0][c * 4];    // wave-uniform -> LDS broadcast
        w1.u = *(const uint4*)&Wh[1][c * 4];
#pragma unroll
        for (int dp = 0; dp < 4; ++dp) {
            const __half2 aa = a0.h[dp];
            const __half2 bb[2] = { b0.h[dp], b1.h[dp] };
            const __half2 wc0 = w0.h[dp], wc1 = w1.h[dp];
#pragma unroll
            for (int jj = 0; jj < 2; ++jj) {
                const __half2 x  = __hadd2(aa, bb[jj]);
                const __half2 t  = __hmul2(x, CS);    // -2.45547*x
                const __half2 e  = h2exp2(t);         // 2^t; overflow->inf, underflow->0
                const __half2 dn = __hadd2(e, ONE);
                const __half2 r  = h2rcp(dn);         // rcp(inf)=0 -> g=0 (x->-inf limit ok)
                const __half2 g  = __hmul2(x, r);     // g = x*sigma(1.702x) ~ gelu(x)
                float* l = acc[jj];
                l[0] = fdot2_acc(g, wc0, l[0]);
                l[1] = fdot2_acc(g, wc1, l[1]);
            }
        }
    }

#pragma unroll
    for (int jj = 0; jj < 2; ++jj) {
        const int i = bi + ty;
        const int j = bj + tx + 16 * jj;
        const float* l = acc[jj];
        const float l0 = l[0], l1 = l[1];                // l2 == 0
        const float mm = fmaxf(fmaxf(l0, l1), 0.f);
        const float e0 = __expf(l0 - mm), e1 = __expf(l1 - mm), e2 = __expf(-mm);
        const float inv2 = 1.0f / (e0 + e1 + e2);
        float* o = pout + ((size_t)i * N + j) * 3;
        o[0] = e0 * inv2; o[1] = e1 * inv2; o[2] = e2 * inv2;
    }
}

extern "C" void kernel_launch(void* const* d_in, const int* in_sizes, int n_in,
                              void* d_out, int out_size, void* d_ws, size_t ws_size,
                              hipStream_t stream)
{
    const float* z    = (const float*)d_in[0];
    const float* dist = (const float*)d_in[1];
    const float* Wq   = (const float*)d_in[2];
    const float* bq   = (const float*)d_in[3];
    const float* Wk   = (const float*)d_in[4];
    const float* bk   = (const float*)d_in[5];
    const float* W1   = (const float*)d_in[6];
    const float* b1   = (const float*)d_in[7];
    const float* W2   = (const float*)d_in[8];
    const float* b2   = (const float*)d_in[9];

    float* out = (float*)d_out;
    __half* Qh = (__half*)d_ws;
    __half* Kh = Qh + (size_t)N * D;
    __half* Ah = Kh + (size_t)N * D;
    __half* Bh = Ah + (size_t)N * D;

    proj_kernel<<<N / 4, 256, 0, stream>>>(z, Wq, bq, Wk, bk, W1, b1, Qh, Kh, Ah, Bh);
    score_kernel<<<dim3(N / 32, N / 32), 256, 0, stream>>>(Qh, Kh, dist, out);
    tp_kernel<<<2304, 256, 0, stream>>>(Ah, Bh, W2, b2, out);
}